// Round 25
// baseline (345.930 us; speedup 1.0000x reference)
//
#include <hip/hip_runtime.h>
#include <hip/hip_bf16.h>

#define N_CELLS  200000
#define N_FACES  400000
#define N_POINTS 200000
#define E_CF     800000
#define E_FP     800000
#define E_PP     1200000
#define CAP_CF   16
#define CAP_FP   24
#define CAP_PP   32
#define OVF_CAP  4096
#define PP_SPLIT 100000   // pp rows [0,100k) filled in A, [100k,200k) in B

typedef __attribute__((ext_vector_type(4))) float f32x4;
typedef __attribute__((ext_vector_type(8))) unsigned short u16x8;

__device__ __forceinline__ float bf2f(unsigned short u) {
    union { unsigned int i; float f; } v; v.i = ((unsigned int)u) << 16; return v.f;
}
__device__ __forceinline__ unsigned short f2bf(float f) {
    __hip_bfloat16 h = __float2bfloat16(f);
    return *reinterpret_cast<unsigned short*>(&h);
}
__device__ __forceinline__ int2 ldnt2(const int2* p) {
    long long v = __builtin_nontemporal_load((const long long*)p);
    int2 r; r.x = (int)(v & 0xffffffffLL); r.y = (int)(v >> 32); return r;
}

// ======== fixed-stride fill helper (2-partition sweep) ========
__device__ __forceinline__ void fill_fixed(const int* __restrict__ src,
                                           const int* __restrict__ dst,
                                           const float* __restrict__ ea,
                                           int nE, int rlo, int rhi, int cap,
                                           int tid0, int stride,
                                           int* __restrict__ cnt,
                                           int2* __restrict__ pe,
                                           int* __restrict__ ovfn,
                                           int4* __restrict__ ovf) {
    for (int e = tid0; e < nE; e += stride) {
        int4 d4 = *(const int4*)(dst + e);
        int4 s4 = *(const int4*)(src + e);
        float4 w4 = *(const float4*)(ea + e);
        int dd[4] = {d4.x, d4.y, d4.z, d4.w};
        int ss[4] = {s4.x, s4.y, s4.z, s4.w};
        float ww[4] = {w4.x, w4.y, w4.z, w4.w};
#pragma unroll
        for (int i = 0; i < 4; ++i) {
            int d = dd[i];
            if (d >= rlo && d < rhi) {
                int t = atomicAdd(&cnt[d], 1);
                if (t < cap)
                    pe[(size_t)d * cap + t] = make_int2(ss[i], __float_as_int(ww[i]));
                else {
                    int g = atomicAdd(ovfn, 1);
                    if (g < OVF_CAP) ovf[g] = make_int4(d, ss[i], __float_as_int(ww[i]), 0);
                }
            }
        }
    }
}

// ======== LAUNCH A: fill_cf ∥ fill_pp[0,100k) ∥ W36 precompute ========
// W36 rows: 0-15 = Wt3[a], 16 = Wt3[s], 17-32 = Wt2[a], 33 = Wt2[s], 34 = Wt2[1], 35 = Wt3[1]+b_pp
__global__ __launch_bounds__(256) void k_fillA(const int* __restrict__ src_cf,
                                               const int* __restrict__ dst_cf,
                                               const float* __restrict__ ea_cf,
                                               int* __restrict__ cnt_cf,
                                               int2* __restrict__ pe_cf,
                                               const int* __restrict__ src_pp,
                                               const int* __restrict__ dst_pp,
                                               const float* __restrict__ ea_pp,
                                               int* __restrict__ cnt_pp,
                                               int2* __restrict__ pe_pp,
                                               int* __restrict__ ovfn,
                                               int4* __restrict__ ovf_cf,
                                               int4* __restrict__ ovf_pp,
                                               const float* __restrict__ W_cf,
                                               const float* __restrict__ b_cf,
                                               const float* __restrict__ W_fp,
                                               const float* __restrict__ b_fp,
                                               const float* __restrict__ W_rt,
                                               const float* __restrict__ W_pp,
                                               const float* __restrict__ b_pp,
                                               float* __restrict__ WALL) {
    __shared__ float WcfS[512];
    __shared__ float bcfS[64];
    __shared__ float WtL[18 * 128];
    int b = blockIdx.x;
    if (b < 512) {                                // fill cf (2 partitions x 256 blocks)
        int p = b & 1;
        int blk = b >> 1;
        int rlo = p * 200000, rhi = rlo + 200000;
        int tid0 = (blk * 256 + (int)threadIdx.x) * 4;
        fill_fixed(src_cf, dst_cf, ea_cf, E_CF, rlo, rhi, CAP_CF,
                   tid0, 256 * 256 * 4, cnt_cf, pe_cf, ovfn, ovf_cf);
    } else if (b < 1024) {                        // fill pp rows [0, PP_SPLIT)
        int bb = b - 512;
        int p = bb & 1;
        int blk = bb >> 1;
        int rlo = p * 50000, rhi = rlo + 50000;
        int tid0 = (blk * 256 + (int)threadIdx.x) * 4;
        fill_fixed(src_pp, dst_pp, ea_pp, E_PP, rlo, rhi, CAP_PP,
                   tid0, 256 * 256 * 4, cnt_pp, pe_pp, ovfn + 2, ovf_pp);
    } else {                                      // W precompute (1 block)
        for (int i = threadIdx.x; i < 512; i += 256) WcfS[i] = W_cf[i];
        if (threadIdx.x < 64) bcfS[threadIdx.x] = b_cf[threadIdx.x];
        __syncthreads();
        int t = threadIdx.x;
        int j = t & 127;
        if (t < 128) {
            float accW[8] = {};
            float accb = 0.f;
            for (int m = 0; m < 64; ++m) {
                float wf = W_fp[m * 128 + j];
#pragma unroll
                for (int k = 0; k < 8; ++k) accW[k] += WcfS[k * 64 + m] * wf;
                accb += bcfS[m] * wf;
            }
#pragma unroll
            for (int k = 0; k < 8; ++k) WtL[k * 128 + j] = accW[k];
            WtL[16 * 128 + j] = accb;
        } else {
#pragma unroll
            for (int k = 0; k < 8; ++k) WtL[(8 + k) * 128 + j] = W_fp[(64 + k) * 128 + j];
            WtL[17 * 128 + j] = b_fp[j];
        }
        __syncthreads();
        for (int i = threadIdx.x; i < 36 * 128; i += 256) {
            int r = i >> 7, jj = i & 127;
            float acc;
            if (r < 17) {
                acc = 0.f;
                for (int k = 0; k < 128; ++k) acc += WtL[r * 128 + k] * W_rt[k * 128 + jj];
            } else if (r < 34) {
                acc = 0.f;
                for (int k = 0; k < 128; ++k) acc += WtL[(r - 17) * 128 + k] * W_pp[k * 128 + jj];
            } else if (r == 34) {
                acc = 0.f;
                for (int k = 0; k < 128; ++k) acc += WtL[17 * 128 + k] * W_pp[k * 128 + jj];
            } else {
                acc = b_pp[jj];
                for (int k = 0; k < 128; ++k) acc += WtL[17 * 128 + k] * W_rt[k * 128 + jj];
            }
            WALL[i] = acc;
        }
    }
}

// ======== LAUNCH B: fill_fp ∥ fill_pp[100k,200k) ∥ aggcx-gather (bf16 out) ========
__global__ __launch_bounds__(256) void k_fillB(const int* __restrict__ src_fp,
                                               const int* __restrict__ dst_fp,
                                               const float* __restrict__ ea_fp,
                                               int* __restrict__ cnt_fp,
                                               int2* __restrict__ pe_fp,
                                               const int* __restrict__ src_pp,
                                               const int* __restrict__ dst_pp,
                                               const float* __restrict__ ea_pp,
                                               int* __restrict__ cnt_pp,
                                               int2* __restrict__ pe_pp,
                                               int* __restrict__ ovfn,
                                               int4* __restrict__ ovf_fp,
                                               int4* __restrict__ ovf_pp,
                                               const float* __restrict__ xc,
                                               const int* __restrict__ cnt_cf,
                                               const int2* __restrict__ pe_cf,
                                               const int* __restrict__ ovfn_cf,
                                               const int4* __restrict__ ovf_cf,
                                               const float* __restrict__ x_face,
                                               unsigned short* __restrict__ aggcx) {
    int b = blockIdx.x;
    if (b < 512) {                                // ---- fill fp ----
        int p = b & 1;
        int blk = b >> 1;
        int rlo = p * 100000, rhi = rlo + 100000;
        int tid0 = (blk * 256 + (int)threadIdx.x) * 4;
        fill_fixed(src_fp, dst_fp, ea_fp, E_FP, rlo, rhi, CAP_FP,
                   tid0, 256 * 256 * 4, cnt_fp, pe_fp, ovfn + 1, ovf_fp);
        return;
    }
    if (b < 1024) {                               // ---- fill pp rows [PP_SPLIT, 200000) ----
        int bb = b - 512;
        int p = bb & 1;
        int blk = bb >> 1;
        int rlo = PP_SPLIT + p * 50000, rhi = rlo + 50000;
        int tid0 = (blk * 256 + (int)threadIdx.x) * 4;
        fill_fixed(src_pp, dst_pp, ea_pp, E_PP, rlo, rhi, CAP_PP,
                   tid0, 256 * 256 * 4, cnt_pp, pe_pp, ovfn + 2, ovf_pp);
        return;
    }
    // ---- aggcx gather: one thread per face row, bf16 output ----
    int r = (b - 1024) * 256 + threadIdx.x;
    if (r >= N_FACES) return;
    int n = cnt_cf[r]; if (n > CAP_CF) n = CAP_CF;
    const int2* prow = pe_cf + (size_t)r * CAP_CF;
    float a[8] = {};
    int e = 0;
    for (; e + 1 < n; e += 2) {
        int2 q0 = prow[e], q1 = prow[e + 1];
        float w0 = __int_as_float(q0.y), w1 = __int_as_float(q1.y);
        const float* p0 = xc + (size_t)q0.x * 8;
        const float* p1 = xc + (size_t)q1.x * 8;
        float4 u0 = *(const float4*)p0, u1 = *(const float4*)(p0 + 4);
        float4 v0 = *(const float4*)p1, v1 = *(const float4*)(p1 + 4);
        a[0] += w0 * u0.x + w1 * v0.x; a[1] += w0 * u0.y + w1 * v0.y;
        a[2] += w0 * u0.z + w1 * v0.z; a[3] += w0 * u0.w + w1 * v0.w;
        a[4] += w0 * u1.x + w1 * v1.x; a[5] += w0 * u1.y + w1 * v1.y;
        a[6] += w0 * u1.z + w1 * v1.z; a[7] += w0 * u1.w + w1 * v1.w;
    }
    if (e < n) {
        int2 q0 = prow[e];
        float w0 = __int_as_float(q0.y);
        const float* p0 = xc + (size_t)q0.x * 8;
        float4 u0 = *(const float4*)p0, u1 = *(const float4*)(p0 + 4);
        a[0] += w0 * u0.x; a[1] += w0 * u0.y; a[2] += w0 * u0.z; a[3] += w0 * u0.w;
        a[4] += w0 * u1.x; a[5] += w0 * u1.y; a[6] += w0 * u1.z; a[7] += w0 * u1.w;
    }
    int no = *ovfn_cf;
    if (no > 0) {
        if (no > OVF_CAP) no = OVF_CAP;
        for (int i = 0; i < no; ++i) {
            int4 o = ovf_cf[i];
            if (o.x == r) {
                float w0 = __int_as_float(o.z);
                const float* p0 = xc + (size_t)o.y * 8;
#pragma unroll
                for (int k = 0; k < 8; ++k) a[k] += w0 * p0[k];
            }
        }
    }
    float4 xf0 = *(const float4*)(x_face + (size_t)r * 8);
    float4 xf1 = *(const float4*)(x_face + (size_t)r * 8 + 4);
    u16x8 o0, o1;
#pragma unroll
    for (int i = 0; i < 8; ++i) o0[i] = f2bf(a[i]);
    o1[0] = f2bf(xf0.x); o1[1] = f2bf(xf0.y); o1[2] = f2bf(xf0.z); o1[3] = f2bf(xf0.w);
    o1[4] = f2bf(xf1.x); o1[5] = f2bf(xf1.y); o1[6] = f2bf(xf1.z); o1[7] = f2bf(xf1.w);
    unsigned short* orow = aggcx + (size_t)r * 16;
    *(u16x8*)orow = o0;
    *(u16x8*)(orow + 8) = o1;
}

// ======== LAUNCH C: 16-lane-per-point gather-only -> a16b(bf16)[200k][16], s_fp[200k] ========
__global__ __launch_bounds__(256) void k_g16(const unsigned short* __restrict__ aggcx,
                                             const int* __restrict__ cnt,
                                             const int2* __restrict__ pe,
                                             const int* __restrict__ ovfn,
                                             const int4* __restrict__ ovf,
                                             unsigned short* __restrict__ a16b,
                                             float* __restrict__ s_fp) {
    const int grp = threadIdx.x >> 4;
    const int l = threadIdx.x & 15;
    const int row = blockIdx.x * 16 + grp;
    int n = cnt[row]; if (n > CAP_FP) n = CAP_FP;
    const int2* prow = pe + (size_t)row * CAP_FP;
    float acc = 0.f, s = 0.f;
    int e = 0;
    for (; e + 1 < n; e += 2) {
        int2 q0 = ldnt2(prow + e);
        int2 q1 = ldnt2(prow + e + 1);
        float w0 = __int_as_float(q0.y), w1 = __int_as_float(q1.y);
        acc += w0 * bf2f(aggcx[(size_t)q0.x * 16 + l]) + w1 * bf2f(aggcx[(size_t)q1.x * 16 + l]);
        s += w0 + w1;
    }
    if (e < n) {
        int2 q0 = ldnt2(prow + e);
        float w0 = __int_as_float(q0.y);
        acc += w0 * bf2f(aggcx[(size_t)q0.x * 16 + l]);
        s += w0;
    }
    int no = *ovfn;
    if (no > 0) {
        if (no > OVF_CAP) no = OVF_CAP;
        for (int i = 0; i < no; ++i) {
            int4 o = ovf[i];
            if (o.x == row) {
                float w0 = __int_as_float(o.z);
                acc += w0 * bf2f(aggcx[(size_t)o.y * 16 + l]);
                s += w0;
            }
        }
    }
    a16b[(size_t)row * 16 + l] = f2bf(acc);
    if (l == 0) s_fp[row] = s;
}

// ======== LAUNCH D: gather a16b/s_fp + K=36 transform (strided cols, conflict-free) ========
__global__ __launch_bounds__(256) void k_fin(const unsigned short* __restrict__ a16b,
                                             const float* __restrict__ s_fp,
                                             const int* __restrict__ cnt,
                                             const int2* __restrict__ pe,
                                             const int* __restrict__ ovfn,
                                             const int4* __restrict__ ovf,
                                             const float* __restrict__ WALL,
                                             float* __restrict__ out) {
    __shared__ float W36[36 * 128];               // 18.4 KB
    for (int i = threadIdx.x; i < 36 * 128; i += 256) W36[i] = WALL[i];
    __syncthreads();
    const int grp = threadIdx.x >> 4;
    const int l = threadIdx.x & 15;
    const int row = blockIdx.x * 16 + grp;
    int n = cnt[row]; if (n > CAP_PP) n = CAP_PP;
    const int2* prow = pe + (size_t)row * CAP_PP;
    float App = 0.f, Spp = 0.f, Tpp = 0.f;
    int e = 0;
    for (; e + 1 < n; e += 2) {
        int2 q0 = ldnt2(prow + e);
        int2 q1 = ldnt2(prow + e + 1);
        float w0 = __int_as_float(q0.y), w1 = __int_as_float(q1.y);
        App += w0 * bf2f(a16b[(size_t)q0.x * 16 + l]) + w1 * bf2f(a16b[(size_t)q1.x * 16 + l]);
        Spp += w0 * s_fp[q0.x] + w1 * s_fp[q1.x];
        Tpp += w0 + w1;
    }
    if (e < n) {
        int2 q0 = ldnt2(prow + e);
        float w0 = __int_as_float(q0.y);
        App += w0 * bf2f(a16b[(size_t)q0.x * 16 + l]);
        Spp += w0 * s_fp[q0.x];
        Tpp += w0;
    }
    int no = *ovfn;
    if (no > 0) {
        if (no > OVF_CAP) no = OVF_CAP;
        for (int i = 0; i < no; ++i) {
            int4 o = ovf[i];
            if (o.x == row) {
                float w0 = __int_as_float(o.z);
                App += w0 * bf2f(a16b[(size_t)o.y * 16 + l]);
                Spp += w0 * s_fp[o.y];
                Tpp += w0;
            }
        }
    }
    float aown = bf2f(a16b[(size_t)row * 16 + l]);
    float sown = s_fp[row];
    // transform: lane l owns strided cols {16k + l}, k=0..7 (bank-conflict-free)
    float o[8];
#pragma unroll
    for (int k = 0; k < 8; ++k) {
        int c = 16 * k + l;
        o[k] = W36[35 * 128 + c] + sown * W36[16 * 128 + c]
             + Spp * W36[33 * 128 + c] + Tpp * W36[34 * 128 + c];
    }
#pragma unroll
    for (int r = 0; r < 16; ++r) {
        float av = __shfl(aown, r, 16);
        const float* wr = W36 + r * 128 + l;
#pragma unroll
        for (int k = 0; k < 8; ++k) o[k] += av * wr[16 * k];
    }
#pragma unroll
    for (int r = 0; r < 16; ++r) {
        float av = __shfl(App, r, 16);
        const float* wr = W36 + (17 + r) * 128 + l;
#pragma unroll
        for (int k = 0; k < 8; ++k) o[k] += av * wr[16 * k];
    }
    float* op = out + (size_t)row * 128 + l;
#pragma unroll
    for (int k = 0; k < 8; ++k)
        __builtin_nontemporal_store(o[k], op + 16 * k);
}

extern "C" void kernel_launch(void* const* d_in, const int* in_sizes, int n_in,
                              void* d_out, int out_size, void* d_ws, size_t ws_size,
                              hipStream_t stream) {
    const float* x_centers = (const float*)d_in[0];
    const float* x_face    = (const float*)d_in[1];
    const float* W_cf      = (const float*)d_in[2];
    const float* b_cf      = (const float*)d_in[3];
    const float* W_fp      = (const float*)d_in[4];
    const float* b_fp      = (const float*)d_in[5];
    const float* W_pp      = (const float*)d_in[6];
    const float* W_rt      = (const float*)d_in[7];
    const float* b_pp      = (const float*)d_in[8];
    const float* ea_cf     = (const float*)d_in[9];
    const float* ea_fp     = (const float*)d_in[10];
    const float* ea_pp     = (const float*)d_in[11];
    const int* src_cf      = (const int*)d_in[12];
    const int* dst_cf      = (const int*)d_in[13];
    const int* src_fp      = (const int*)d_in[14];
    const int* dst_fp      = (const int*)d_in[15];
    const int* src_pp      = (const int*)d_in[16];
    const int* dst_pp      = (const int*)d_in[17];
    float* out = (float*)d_out;

    char* ws = (char*)d_ws;
    unsigned short* aggcx  = (unsigned short*)(ws + 0);           // bf16 [400k][16] 12.8MB
    unsigned short* a16b   = (unsigned short*)(ws + 14000000);    // bf16 [200k][16]  6.4MB
    float* s_fp            = (float*)(ws + 22000000);             // f32 [200k]      0.8MB
    float* WALL            = (float*)(ws + 24000000);             // f32 [36][128]
    int2* pe_fp            = (int2*)(ws + 30000000);              // 38.4MB
    int2* pe_cf            = (int2*)(ws + 70000000);              // 51.2MB
    int2* pe_pp            = (int2*)(ws + 125000000);             // 51.2MB
    int*  cnt_cf           = (int*)(ws + 280000000);              // 400k ints
    int*  cnt_fp           = (int*)(ws + 281600000);              // 200k
    int*  cnt_pp           = (int*)(ws + 282400000);              // 200k
    int*  ovfn             = (int*)(ws + 283200000);              // 4 ints (memset-covered)
    int4* ovf_cf           = (int4*)(ws + 284000000);             // 64KB
    int4* ovf_fp           = (int4*)(ws + 284100000);
    int4* ovf_pp           = (int4*)(ws + 284200000);

    // zero counters (cnt_cf..ovfn contiguous) in one async memset
    (void)hipMemsetAsync(cnt_cf, 0, 3200016, stream);
    // LAUNCH A: fill_cf ∥ fill_pp[0,100k) ∥ W36 precompute
    k_fillA<<<1025, 256, 0, stream>>>(src_cf, dst_cf, ea_cf, cnt_cf, pe_cf,
                                      src_pp, dst_pp, ea_pp, cnt_pp, pe_pp,
                                      ovfn, ovf_cf, ovf_pp,
                                      W_cf, b_cf, W_fp, b_fp, W_rt, W_pp, b_pp,
                                      WALL);
    // LAUNCH B: fill_fp ∥ fill_pp[100k,200k) ∥ aggcx gather (bf16)
    k_fillB<<<1024 + 1563, 256, 0, stream>>>(src_fp, dst_fp, ea_fp, cnt_fp, pe_fp,
                                             src_pp, dst_pp, ea_pp, cnt_pp, pe_pp,
                                             ovfn, ovf_fp, ovf_pp,
                                             x_centers, cnt_cf, pe_cf, ovfn, ovf_cf,
                                             x_face, aggcx);
    // LAUNCH C: gather-only -> a16b (bf16), s_fp
    k_g16<<<12500, 256, 0, stream>>>(aggcx, cnt_fp, pe_fp, ovfn + 1, ovf_fp, a16b, s_fp);
    // LAUNCH D: gather + K=36 transform -> out
    k_fin<<<12500, 256, 0, stream>>>(a16b, s_fp, cnt_pp, pe_pp, ovfn + 2, ovf_pp, WALL, out);
}

// Round 26
// 322.191 us; speedup vs baseline: 1.0737x; 1.0737x over previous
//
#include <hip/hip_runtime.h>
#include <hip/hip_bf16.h>

#define N_CELLS  200000
#define N_FACES  400000
#define N_POINTS 200000
#define E_CF     800000
#define E_FP     800000
#define E_PP     1200000
#define CAP_CF   16
#define CAP_FP   24
#define CAP_PP   32
#define OVF_CAP  4096
#define PP_SPLIT 130000   // pp rows [0,130k) filled in A, [130k,200k) in B

typedef __attribute__((ext_vector_type(4))) float f32x4;

__device__ __forceinline__ float bf2f(unsigned short u) {
    union { unsigned int i; float f; } v; v.i = ((unsigned int)u) << 16; return v.f;
}
__device__ __forceinline__ unsigned short f2bf(float f) {
    __hip_bfloat16 h = __float2bfloat16(f);
    return *reinterpret_cast<unsigned short*>(&h);
}
__device__ __forceinline__ int2 ldnt2(const int2* p) {
    long long v = __builtin_nontemporal_load((const long long*)p);
    int2 r; r.x = (int)(v & 0xffffffffLL); r.y = (int)(v >> 32); return r;
}

// ======== fixed-stride fill helper (partitioned sweep) ========
__device__ __forceinline__ void fill_fixed(const int* __restrict__ src,
                                           const int* __restrict__ dst,
                                           const float* __restrict__ ea,
                                           int nE, int rlo, int rhi, int cap,
                                           int tid0, int stride,
                                           int* __restrict__ cnt,
                                           int2* __restrict__ pe,
                                           int* __restrict__ ovfn,
                                           int4* __restrict__ ovf) {
    for (int e = tid0; e < nE; e += stride) {
        int4 d4 = *(const int4*)(dst + e);
        int4 s4 = *(const int4*)(src + e);
        float4 w4 = *(const float4*)(ea + e);
        int dd[4] = {d4.x, d4.y, d4.z, d4.w};
        int ss[4] = {s4.x, s4.y, s4.z, s4.w};
        float ww[4] = {w4.x, w4.y, w4.z, w4.w};
#pragma unroll
        for (int i = 0; i < 4; ++i) {
            int d = dd[i];
            if (d >= rlo && d < rhi) {
                int t = atomicAdd(&cnt[d], 1);
                if (t < cap)
                    pe[(size_t)d * cap + t] = make_int2(ss[i], __float_as_int(ww[i]));
                else {
                    int g = atomicAdd(ovfn, 1);
                    if (g < OVF_CAP) ovf[g] = make_int4(d, ss[i], __float_as_int(ww[i]), 0);
                }
            }
        }
    }
}

// ======== LAUNCH A: fill_cf ∥ fill_pp[0,130k) ∥ W36 precompute ========
// W36 rows: 0-15 = Wt3[a], 16 = Wt3[s], 17-32 = Wt2[a], 33 = Wt2[s], 34 = Wt2[1], 35 = Wt3[1]+b_pp
__global__ __launch_bounds__(256) void k_fillA(const int* __restrict__ src_cf,
                                               const int* __restrict__ dst_cf,
                                               const float* __restrict__ ea_cf,
                                               int* __restrict__ cnt_cf,
                                               int2* __restrict__ pe_cf,
                                               const int* __restrict__ src_pp,
                                               const int* __restrict__ dst_pp,
                                               const float* __restrict__ ea_pp,
                                               int* __restrict__ cnt_pp,
                                               int2* __restrict__ pe_pp,
                                               int* __restrict__ ovfn,
                                               int4* __restrict__ ovf_cf,
                                               int4* __restrict__ ovf_pp,
                                               const float* __restrict__ W_cf,
                                               const float* __restrict__ b_cf,
                                               const float* __restrict__ W_fp,
                                               const float* __restrict__ b_fp,
                                               const float* __restrict__ W_rt,
                                               const float* __restrict__ W_pp,
                                               const float* __restrict__ b_pp,
                                               float* __restrict__ WALL) {
    __shared__ float WcfS[512];
    __shared__ float bcfS[64];
    __shared__ float WtL[18 * 128];
    int b = blockIdx.x;
    if (b < 512) {                                // fill cf
        int p = b & 3;
        int blk = b >> 2;
        int rlo = p * 100000, rhi = rlo + 100000;
        int tid0 = (blk * 256 + (int)threadIdx.x) * 4;
        fill_fixed(src_cf, dst_cf, ea_cf, E_CF, rlo, rhi, CAP_CF,
                   tid0, 128 * 256 * 4, cnt_cf, pe_cf, ovfn, ovf_cf);
    } else if (b < 1024) {                        // fill pp rows [0, PP_SPLIT)
        int bb = b - 512;
        int p = bb & 3;
        int blk = bb >> 2;
        int rlo = p * 32500, rhi = rlo + 32500;
        int tid0 = (blk * 256 + (int)threadIdx.x) * 4;
        fill_fixed(src_pp, dst_pp, ea_pp, E_PP, rlo, rhi, CAP_PP,
                   tid0, 128 * 256 * 4, cnt_pp, pe_pp, ovfn + 2, ovf_pp);
    } else {                                      // W precompute (1 block)
        for (int i = threadIdx.x; i < 512; i += 256) WcfS[i] = W_cf[i];
        if (threadIdx.x < 64) bcfS[threadIdx.x] = b_cf[threadIdx.x];
        __syncthreads();
        int t = threadIdx.x;
        int j = t & 127;
        if (t < 128) {
            float accW[8] = {};
            float accb = 0.f;
            for (int m = 0; m < 64; ++m) {
                float wf = W_fp[m * 128 + j];
#pragma unroll
                for (int k = 0; k < 8; ++k) accW[k] += WcfS[k * 64 + m] * wf;
                accb += bcfS[m] * wf;
            }
#pragma unroll
            for (int k = 0; k < 8; ++k) WtL[k * 128 + j] = accW[k];
            WtL[16 * 128 + j] = accb;
        } else {
#pragma unroll
            for (int k = 0; k < 8; ++k) WtL[(8 + k) * 128 + j] = W_fp[(64 + k) * 128 + j];
            WtL[17 * 128 + j] = b_fp[j];
        }
        __syncthreads();
        for (int i = threadIdx.x; i < 36 * 128; i += 256) {
            int r = i >> 7, jj = i & 127;
            float acc;
            if (r < 17) {
                acc = 0.f;
                for (int k = 0; k < 128; ++k) acc += WtL[r * 128 + k] * W_rt[k * 128 + jj];
            } else if (r < 34) {
                acc = 0.f;
                for (int k = 0; k < 128; ++k) acc += WtL[(r - 17) * 128 + k] * W_pp[k * 128 + jj];
            } else if (r == 34) {
                acc = 0.f;
                for (int k = 0; k < 128; ++k) acc += WtL[17 * 128 + k] * W_pp[k * 128 + jj];
            } else {
                acc = b_pp[jj];
                for (int k = 0; k < 128; ++k) acc += WtL[17 * 128 + k] * W_rt[k * 128 + jj];
            }
            WALL[i] = acc;
        }
    }
}

// ======== LAUNCH B: fill_fp ∥ fill_pp[130k,200k) ∥ aggcx-gather ========
__global__ __launch_bounds__(256) void k_fillB(const int* __restrict__ src_fp,
                                               const int* __restrict__ dst_fp,
                                               const float* __restrict__ ea_fp,
                                               int* __restrict__ cnt_fp,
                                               int2* __restrict__ pe_fp,
                                               const int* __restrict__ src_pp,
                                               const int* __restrict__ dst_pp,
                                               const float* __restrict__ ea_pp,
                                               int* __restrict__ cnt_pp,
                                               int2* __restrict__ pe_pp,
                                               int* __restrict__ ovfn,
                                               int4* __restrict__ ovf_fp,
                                               int4* __restrict__ ovf_pp,
                                               const float* __restrict__ xc,
                                               const int* __restrict__ cnt_cf,
                                               const int2* __restrict__ pe_cf,
                                               const int* __restrict__ ovfn_cf,
                                               const int4* __restrict__ ovf_cf,
                                               const float* __restrict__ x_face,
                                               float* __restrict__ aggcx) {
    int b = blockIdx.x;
    if (b < 512) {                                // ---- fill fp ----
        int p = b & 3;
        int blk = b >> 2;
        int rlo = p * 50000, rhi = rlo + 50000;
        int tid0 = (blk * 256 + (int)threadIdx.x) * 4;
        fill_fixed(src_fp, dst_fp, ea_fp, E_FP, rlo, rhi, CAP_FP,
                   tid0, 128 * 256 * 4, cnt_fp, pe_fp, ovfn + 1, ovf_fp);
        return;
    }
    if (b < 1024) {                               // ---- fill pp rows [PP_SPLIT, 200000) ----
        int bb = b - 512;
        int p = bb & 3;
        int blk = bb >> 2;
        int rlo = PP_SPLIT + p * 17500, rhi = rlo + 17500;
        int tid0 = (blk * 256 + (int)threadIdx.x) * 4;
        fill_fixed(src_pp, dst_pp, ea_pp, E_PP, rlo, rhi, CAP_PP,
                   tid0, 128 * 256 * 4, cnt_pp, pe_pp, ovfn + 2, ovf_pp);
        return;
    }
    // ---- aggcx gather: one thread per face row ----
    int r = (b - 1024) * 256 + threadIdx.x;
    if (r >= N_FACES) return;
    int n = cnt_cf[r]; if (n > CAP_CF) n = CAP_CF;
    const int2* prow = pe_cf + (size_t)r * CAP_CF;
    float a[8] = {};
    int e = 0;
    for (; e + 1 < n; e += 2) {
        int2 q0 = prow[e], q1 = prow[e + 1];
        float w0 = __int_as_float(q0.y), w1 = __int_as_float(q1.y);
        const float* p0 = xc + (size_t)q0.x * 8;
        const float* p1 = xc + (size_t)q1.x * 8;
        float4 u0 = *(const float4*)p0, u1 = *(const float4*)(p0 + 4);
        float4 v0 = *(const float4*)p1, v1 = *(const float4*)(p1 + 4);
        a[0] += w0 * u0.x + w1 * v0.x; a[1] += w0 * u0.y + w1 * v0.y;
        a[2] += w0 * u0.z + w1 * v0.z; a[3] += w0 * u0.w + w1 * v0.w;
        a[4] += w0 * u1.x + w1 * v1.x; a[5] += w0 * u1.y + w1 * v1.y;
        a[6] += w0 * u1.z + w1 * v1.z; a[7] += w0 * u1.w + w1 * v1.w;
    }
    if (e < n) {
        int2 q0 = prow[e];
        float w0 = __int_as_float(q0.y);
        const float* p0 = xc + (size_t)q0.x * 8;
        float4 u0 = *(const float4*)p0, u1 = *(const float4*)(p0 + 4);
        a[0] += w0 * u0.x; a[1] += w0 * u0.y; a[2] += w0 * u0.z; a[3] += w0 * u0.w;
        a[4] += w0 * u1.x; a[5] += w0 * u1.y; a[6] += w0 * u1.z; a[7] += w0 * u1.w;
    }
    int no = *ovfn_cf;
    if (no > 0) {
        if (no > OVF_CAP) no = OVF_CAP;
        for (int i = 0; i < no; ++i) {
            int4 o = ovf_cf[i];
            if (o.x == r) {
                float w0 = __int_as_float(o.z);
                const float* p0 = xc + (size_t)o.y * 8;
#pragma unroll
                for (int k = 0; k < 8; ++k) a[k] += w0 * p0[k];
            }
        }
    }
    float4 xf0 = *(const float4*)(x_face + (size_t)r * 8);
    float4 xf1 = *(const float4*)(x_face + (size_t)r * 8 + 4);
    float4* o4 = (float4*)(aggcx + (size_t)r * 16);
    o4[0] = make_float4(a[0], a[1], a[2], a[3]);
    o4[1] = make_float4(a[4], a[5], a[6], a[7]);
    o4[2] = xf0;
    o4[3] = xf1;
}

// ======== LAUNCH C: 16-lane-per-point gather-only -> a16b(bf16)[200k][16], s_fp[200k] ========
__global__ __launch_bounds__(256) void k_g16(const float* __restrict__ aggcx,
                                             const int* __restrict__ cnt,
                                             const int2* __restrict__ pe,
                                             const int* __restrict__ ovfn,
                                             const int4* __restrict__ ovf,
                                             unsigned short* __restrict__ a16b,
                                             float* __restrict__ s_fp) {
    const int grp = threadIdx.x >> 4;
    const int l = threadIdx.x & 15;
    const int row = blockIdx.x * 16 + grp;
    int n = cnt[row]; if (n > CAP_FP) n = CAP_FP;
    const int2* prow = pe + (size_t)row * CAP_FP;
    float acc = 0.f, s = 0.f;
    int e = 0;
    for (; e + 1 < n; e += 2) {
        int2 q0 = ldnt2(prow + e);
        int2 q1 = ldnt2(prow + e + 1);
        float w0 = __int_as_float(q0.y), w1 = __int_as_float(q1.y);
        acc += w0 * aggcx[(size_t)q0.x * 16 + l] + w1 * aggcx[(size_t)q1.x * 16 + l];
        s += w0 + w1;
    }
    if (e < n) {
        int2 q0 = ldnt2(prow + e);
        float w0 = __int_as_float(q0.y);
        acc += w0 * aggcx[(size_t)q0.x * 16 + l];
        s += w0;
    }
    int no = *ovfn;
    if (no > 0) {
        if (no > OVF_CAP) no = OVF_CAP;
        for (int i = 0; i < no; ++i) {
            int4 o = ovf[i];
            if (o.x == row) {
                float w0 = __int_as_float(o.z);
                acc += w0 * aggcx[(size_t)o.y * 16 + l];
                s += w0;
            }
        }
    }
    a16b[(size_t)row * 16 + l] = f2bf(acc);
    if (l == 0) s_fp[row] = s;
}

// ======== LAUNCH D: gather a16b/s_fp + K=36 transform (strided cols, conflict-free) ========
__global__ __launch_bounds__(256) void k_fin(const unsigned short* __restrict__ a16b,
                                             const float* __restrict__ s_fp,
                                             const int* __restrict__ cnt,
                                             const int2* __restrict__ pe,
                                             const int* __restrict__ ovfn,
                                             const int4* __restrict__ ovf,
                                             const float* __restrict__ WALL,
                                             float* __restrict__ out) {
    __shared__ float W36[36 * 128];               // 18.4 KB
    for (int i = threadIdx.x; i < 36 * 128; i += 256) W36[i] = WALL[i];
    __syncthreads();
    const int grp = threadIdx.x >> 4;
    const int l = threadIdx.x & 15;
    const int row = blockIdx.x * 16 + grp;
    int n = cnt[row]; if (n > CAP_PP) n = CAP_PP;
    const int2* prow = pe + (size_t)row * CAP_PP;
    float App = 0.f, Spp = 0.f, Tpp = 0.f;
    int e = 0;
    for (; e + 1 < n; e += 2) {
        int2 q0 = ldnt2(prow + e);
        int2 q1 = ldnt2(prow + e + 1);
        float w0 = __int_as_float(q0.y), w1 = __int_as_float(q1.y);
        App += w0 * bf2f(a16b[(size_t)q0.x * 16 + l]) + w1 * bf2f(a16b[(size_t)q1.x * 16 + l]);
        Spp += w0 * s_fp[q0.x] + w1 * s_fp[q1.x];
        Tpp += w0 + w1;
    }
    if (e < n) {
        int2 q0 = ldnt2(prow + e);
        float w0 = __int_as_float(q0.y);
        App += w0 * bf2f(a16b[(size_t)q0.x * 16 + l]);
        Spp += w0 * s_fp[q0.x];
        Tpp += w0;
    }
    int no = *ovfn;
    if (no > 0) {
        if (no > OVF_CAP) no = OVF_CAP;
        for (int i = 0; i < no; ++i) {
            int4 o = ovf[i];
            if (o.x == row) {
                float w0 = __int_as_float(o.z);
                App += w0 * bf2f(a16b[(size_t)o.y * 16 + l]);
                Spp += w0 * s_fp[o.y];
                Tpp += w0;
            }
        }
    }
    float aown = bf2f(a16b[(size_t)row * 16 + l]);
    float sown = s_fp[row];
    // transform: lane l owns strided cols {16k + l}, k=0..7 (bank-conflict-free)
    float o[8];
#pragma unroll
    for (int k = 0; k < 8; ++k) {
        int c = 16 * k + l;
        o[k] = W36[35 * 128 + c] + sown * W36[16 * 128 + c]
             + Spp * W36[33 * 128 + c] + Tpp * W36[34 * 128 + c];
    }
#pragma unroll
    for (int r = 0; r < 16; ++r) {
        float av = __shfl(aown, r, 16);
        const float* wr = W36 + r * 128 + l;
#pragma unroll
        for (int k = 0; k < 8; ++k) o[k] += av * wr[16 * k];
    }
#pragma unroll
    for (int r = 0; r < 16; ++r) {
        float av = __shfl(App, r, 16);
        const float* wr = W36 + (17 + r) * 128 + l;
#pragma unroll
        for (int k = 0; k < 8; ++k) o[k] += av * wr[16 * k];
    }
    float* op = out + (size_t)row * 128 + l;
#pragma unroll
    for (int k = 0; k < 8; ++k)
        __builtin_nontemporal_store(o[k], op + 16 * k);
}

extern "C" void kernel_launch(void* const* d_in, const int* in_sizes, int n_in,
                              void* d_out, int out_size, void* d_ws, size_t ws_size,
                              hipStream_t stream) {
    const float* x_centers = (const float*)d_in[0];
    const float* x_face    = (const float*)d_in[1];
    const float* W_cf      = (const float*)d_in[2];
    const float* b_cf      = (const float*)d_in[3];
    const float* W_fp      = (const float*)d_in[4];
    const float* b_fp      = (const float*)d_in[5];
    const float* W_pp      = (const float*)d_in[6];
    const float* W_rt      = (const float*)d_in[7];
    const float* b_pp      = (const float*)d_in[8];
    const float* ea_cf     = (const float*)d_in[9];
    const float* ea_fp     = (const float*)d_in[10];
    const float* ea_pp     = (const float*)d_in[11];
    const int* src_cf      = (const int*)d_in[12];
    const int* dst_cf      = (const int*)d_in[13];
    const int* src_fp      = (const int*)d_in[14];
    const int* dst_fp      = (const int*)d_in[15];
    const int* src_pp      = (const int*)d_in[16];
    const int* dst_pp      = (const int*)d_in[17];
    float* out = (float*)d_out;

    char* ws = (char*)d_ws;
    float* aggcx           = (float*)(ws + 0);                    // f32 [400k][16]  25.6MB
    unsigned short* a16b   = (unsigned short*)(ws + 28000000);    // bf16 [200k][16]  6.4MB
    float* s_fp            = (float*)(ws + 36000000);             // f32 [200k]      0.8MB
    float* WALL            = (float*)(ws + 44000000);             // f32 [36][128]
    int2* pe_fp            = (int2*)(ws + 50000000);              // 38.4MB
    int2* pe_cf            = (int2*)(ws + 90000000);              // 51.2MB
    int2* pe_pp            = (int2*)(ws + 145000000);             // 51.2MB
    int*  cnt_cf           = (int*)(ws + 280000000);              // 400k ints
    int*  cnt_fp           = (int*)(ws + 281600000);              // 200k
    int*  cnt_pp           = (int*)(ws + 282400000);              // 200k
    int*  ovfn             = (int*)(ws + 283200000);              // 4 ints (memset-covered)
    int4* ovf_cf           = (int4*)(ws + 284000000);             // 64KB
    int4* ovf_fp           = (int4*)(ws + 284100000);
    int4* ovf_pp           = (int4*)(ws + 284200000);

    // zero counters (cnt_cf..ovfn contiguous) in one async memset
    (void)hipMemsetAsync(cnt_cf, 0, 3200016, stream);
    // LAUNCH A: fill_cf ∥ fill_pp[0,130k) ∥ W36 precompute
    k_fillA<<<1025, 256, 0, stream>>>(src_cf, dst_cf, ea_cf, cnt_cf, pe_cf,
                                      src_pp, dst_pp, ea_pp, cnt_pp, pe_pp,
                                      ovfn, ovf_cf, ovf_pp,
                                      W_cf, b_cf, W_fp, b_fp, W_rt, W_pp, b_pp,
                                      WALL);
    // LAUNCH B: fill_fp ∥ fill_pp[130k,200k) ∥ aggcx gather
    k_fillB<<<1024 + 1563, 256, 0, stream>>>(src_fp, dst_fp, ea_fp, cnt_fp, pe_fp,
                                             src_pp, dst_pp, ea_pp, cnt_pp, pe_pp,
                                             ovfn, ovf_fp, ovf_pp,
                                             x_centers, cnt_cf, pe_cf, ovfn, ovf_cf,
                                             x_face, aggcx);
    // LAUNCH C: gather-only -> a16b (bf16), s_fp
    k_g16<<<12500, 256, 0, stream>>>(aggcx, cnt_fp, pe_fp, ovfn + 1, ovf_fp, a16b, s_fp);
    // LAUNCH D: gather + K=36 transform -> out
    k_fin<<<12500, 256, 0, stream>>>(a16b, s_fp, cnt_pp, pe_pp, ovfn + 2, ovf_pp, WALL, out);
}